// Round 2
// baseline (1141.662 us; speedup 1.0000x reference)
//
#include <hip/hip_runtime.h>

#define NSLOPE 0.01f
#define DF 128  // feature dim

// ---------------- CSR build ----------------
// edge_index arrives as int32 (harness converts all integer inputs to int32).

__global__ __launch_bounds__(256) void count_kernel(const int* __restrict__ ei,
                                                    int* __restrict__ cnt, int E) {
    int e = blockIdx.x * 256 + threadIdx.x;
    if (e < E) atomicAdd(&cnt[ei[E + e]], 1);
}

__global__ __launch_bounds__(1024) void scan_kernel(const int* __restrict__ cnt,
                                                    int* __restrict__ rowstart, int n) {
    __shared__ int sums[1024];
    int t = threadIdx.x;
    int chunk = (n + 1023) >> 10;
    int start = t * chunk;
    int end = min(start + chunk, n);
    int s = 0;
    for (int i = start; i < end; ++i) s += cnt[i];
    sums[t] = s;
    __syncthreads();
    for (int off = 1; off < 1024; off <<= 1) {
        int v = (t >= off) ? sums[t - off] : 0;
        __syncthreads();
        sums[t] += v;
        __syncthreads();
    }
    int run = (t == 0) ? 0 : sums[t - 1];
    for (int i = start; i < end; ++i) { rowstart[i] = run; run += cnt[i]; }
    if (t == 1023) rowstart[n] = sums[1023];
}

__global__ __launch_bounds__(256) void fill_kernel(const int* __restrict__ ei,
                                                   const int* __restrict__ rowstart,
                                                   int* __restrict__ cursor,
                                                   int* __restrict__ csr, int E) {
    int e = blockIdx.x * 256 + threadIdx.x;
    if (e < E) {
        int d = ei[E + e];
        int pos = atomicAdd(&cursor[d], 1);
        csr[rowstart[d] + pos] = ei[e];
    }
}

__global__ __launch_bounds__(256) void dinv_kernel(const int* __restrict__ cnt,
                                                   float* __restrict__ dinv, int n) {
    int v = blockIdx.x * 256 + threadIdx.x;
    if (v < n) dinv[v] = rsqrtf((float)(cnt[v] + 1));  // +1 self loop
}

// ---------------- fused LeakyReLU + GEMM ----------------
// H[row][c] = sum_k lrelu(X[row][k]) * W[k][c]
// thread: 1 row x 4 cols; 32 threads cover the 128 cols of one row.

__global__ __launch_bounds__(256) void gemm_lrelu(const float* __restrict__ X,
                                                  const float* __restrict__ W,
                                                  float* __restrict__ H, int n) {
    int gid = blockIdx.x * 256 + threadIdx.x;
    int row = gid >> 5;
    if (row >= n) return;
    int cg = (gid & 31) << 2;
    const float4* X4 = (const float4*)(X + (size_t)row * DF);
    const float* Wc = W + cg;
    float4 acc = make_float4(0.f, 0.f, 0.f, 0.f);
#pragma unroll 4
    for (int k4 = 0; k4 < DF / 4; ++k4) {
        float4 xv = X4[k4];
        xv.x = xv.x > 0.f ? xv.x : NSLOPE * xv.x;
        xv.y = xv.y > 0.f ? xv.y : NSLOPE * xv.y;
        xv.z = xv.z > 0.f ? xv.z : NSLOPE * xv.z;
        xv.w = xv.w > 0.f ? xv.w : NSLOPE * xv.w;
        float4 w0 = *(const float4*)(Wc + (size_t)(k4 * 4 + 0) * DF);
        float4 w1 = *(const float4*)(Wc + (size_t)(k4 * 4 + 1) * DF);
        float4 w2 = *(const float4*)(Wc + (size_t)(k4 * 4 + 2) * DF);
        float4 w3 = *(const float4*)(Wc + (size_t)(k4 * 4 + 3) * DF);
        acc.x += xv.x * w0.x; acc.y += xv.x * w0.y; acc.z += xv.x * w0.z; acc.w += xv.x * w0.w;
        acc.x += xv.y * w1.x; acc.y += xv.y * w1.y; acc.z += xv.y * w1.z; acc.w += xv.y * w1.w;
        acc.x += xv.z * w2.x; acc.y += xv.z * w2.y; acc.z += xv.z * w2.z; acc.w += xv.z * w2.w;
        acc.x += xv.w * w3.x; acc.y += xv.w * w3.y; acc.z += xv.w * w3.z; acc.w += xv.w * w3.w;
    }
    *(float4*)(H + (size_t)row * DF + cg) = acc;
}

// ---------------- aggregation: one wave64 per node ----------------
// out[v] = b + dinv[v]^2 * H[v] + sum_{e: dst=v} dinv[src]*dinv[v] * H[src]

__global__ __launch_bounds__(256) void agg_kernel(const float* __restrict__ H,
                                                  const float* __restrict__ dinv,
                                                  const int* __restrict__ rowstart,
                                                  const int* __restrict__ csr,
                                                  const float* __restrict__ b,
                                                  float* __restrict__ out, int n) {
    int v = (blockIdx.x * 256 + threadIdx.x) >> 6;
    int lane = threadIdx.x & 63;
    if (v >= n) return;
    float dv = dinv[v];
    const float2* H2 = (const float2*)H;
    float2 hv = H2[(size_t)v * 64 + lane];
    float2 bb = ((const float2*)b)[lane];
    float sw = dv * dv;
    float2 acc;
    acc.x = hv.x * sw + bb.x;
    acc.y = hv.y * sw + bb.y;
    int j0 = rowstart[v], j1 = rowstart[v + 1];
    for (int j = j0; j < j1; ++j) {
        int s = csr[j];
        float w = dinv[s] * dv;
        float2 hs = H2[(size_t)s * 64 + lane];
        acc.x += hs.x * w;
        acc.y += hs.y * w;
    }
    ((float2*)out)[(size_t)v * 64 + lane] = acc;
}

extern "C" void kernel_launch(void* const* d_in, const int* in_sizes, int n_in,
                              void* d_out, int out_size, void* d_ws, size_t ws_size,
                              hipStream_t stream) {
    const float* x = (const float*)d_in[0];
    const int* ei = (const int*)d_in[1];
    const float* W1 = (const float*)d_in[2];
    const float* b1 = (const float*)d_in[3];
    const float* W2 = (const float*)d_in[4];
    const float* b2 = (const float*)d_in[5];
    const float* W3 = (const float*)d_in[6];
    const float* b3 = (const float*)d_in[7];
    float* out = (float*)d_out;

    const int N = in_sizes[0] / DF;
    const int E = in_sizes[1] / 2;

    char* ws = (char*)d_ws;
    size_t off = 0;
    auto alloc = [&](size_t bytes) {
        size_t o = off;
        off = (off + bytes + 15) & ~(size_t)15;
        return o;
    };
    int* cnt      = (int*)(ws + alloc((size_t)N * 4));
    int* cursor   = (int*)(ws + alloc((size_t)N * 4));
    float* dinv   = (float*)(ws + alloc((size_t)N * 4));
    int* rowstart = (int*)(ws + alloc((size_t)(N + 1) * 4));
    int* csr      = (int*)(ws + alloc((size_t)E * 4));
    float* H      = (float*)(ws + alloc((size_t)N * DF * 4));

    // zero cnt + cursor (adjacent at the front of ws)
    hipMemsetAsync(ws, 0, (size_t)N * 8, stream);

    int eb = (E + 255) / 256;
    count_kernel<<<eb, 256, 0, stream>>>(ei, cnt, E);
    scan_kernel<<<1, 1024, 0, stream>>>(cnt, rowstart, N);
    fill_kernel<<<eb, 256, 0, stream>>>(ei, rowstart, cursor, csr, E);
    dinv_kernel<<<(N + 255) / 256, 256, 0, stream>>>(cnt, dinv, N);

    int gemm_blocks = (N * 32 + 255) / 256;
    int agg_blocks = (N * 64 + 255) / 256;

    // layer 1
    gemm_lrelu<<<gemm_blocks, 256, 0, stream>>>(x, W1, H, N);
    agg_kernel<<<agg_blocks, 256, 0, stream>>>(H, dinv, rowstart, csr, b1, out, N);
    // layer 2
    gemm_lrelu<<<gemm_blocks, 256, 0, stream>>>(out, W2, H, N);
    agg_kernel<<<agg_blocks, 256, 0, stream>>>(H, dinv, rowstart, csr, b2, out, N);
    // layer 3
    gemm_lrelu<<<gemm_blocks, 256, 0, stream>>>(out, W3, H, N);
    agg_kernel<<<agg_blocks, 256, 0, stream>>>(H, dinv, rowstart, csr, b3, out, N);
}

// Round 3
// 721.491 us; speedup vs baseline: 1.5824x; 1.5824x over previous
//
#include <hip/hip_runtime.h>

#define NSLOPE 0.01f
#define DF 128  // feature dim
#define RPB 32  // rows per block in gemm

// ---------------- CSR build ----------------
// edge_index arrives as int32 (harness converts all integer inputs to int32).

__global__ __launch_bounds__(256) void count_kernel(const int* __restrict__ ei,
                                                    int* __restrict__ cnt, int E) {
    int e = blockIdx.x * 256 + threadIdx.x;
    if (e < E) atomicAdd(&cnt[ei[E + e]], 1);
}

__global__ __launch_bounds__(1024) void scan_kernel(const int* __restrict__ cnt,
                                                    int* __restrict__ rowstart, int n) {
    __shared__ int sums[1024];
    int t = threadIdx.x;
    int chunk = (n + 1023) >> 10;
    int start = t * chunk;
    int end = min(start + chunk, n);
    int s = 0;
    for (int i = start; i < end; ++i) s += cnt[i];
    sums[t] = s;
    __syncthreads();
    for (int off = 1; off < 1024; off <<= 1) {
        int v = (t >= off) ? sums[t - off] : 0;
        __syncthreads();
        sums[t] += v;
        __syncthreads();
    }
    int run = (t == 0) ? 0 : sums[t - 1];
    for (int i = start; i < end; ++i) { rowstart[i] = run; run += cnt[i]; }
    if (t == 1023) rowstart[n] = sums[1023];
}

__global__ __launch_bounds__(256) void fill_kernel(const int* __restrict__ ei,
                                                   const int* __restrict__ rowstart,
                                                   int* __restrict__ cursor,
                                                   int* __restrict__ csr, int E) {
    int e = blockIdx.x * 256 + threadIdx.x;
    if (e < E) {
        int d = ei[E + e];
        int pos = atomicAdd(&cursor[d], 1);
        csr[rowstart[d] + pos] = ei[e];
    }
}

__global__ __launch_bounds__(256) void dinv_kernel(const int* __restrict__ cnt,
                                                   float* __restrict__ dinv, int n) {
    int v = blockIdx.x * 256 + threadIdx.x;
    if (v < n) dinv[v] = rsqrtf((float)(cnt[v] + 1));  // +1 self loop
}

// ---------------- fused LeakyReLU + GEMM ----------------
// H[row][c] = sum_k lrelu(X[row][k]) * W[k][c]
// Block: 32 rows. W (64KB) + lrelu(X) tile (16KB) staged in LDS.
// Thread: 4 rows x 4 cols register tile. 32 colgroups x 8 rowgroups = 256 thr.

__global__ __launch_bounds__(256) void gemm_lrelu(const float* __restrict__ X,
                                                  const float* __restrict__ W,
                                                  float* __restrict__ H, int n) {
    __shared__ float Ws[DF * DF];    // 64 KB
    __shared__ float Xs[RPB * DF];   // 16 KB

    int tid = threadIdx.x;
    int row_base = blockIdx.x * RPB;

    // stage W: 128*128 floats = 4096 float4, 256 thr -> 16 iters, coalesced
    const float4* W4 = (const float4*)W;
    float4* Ws4 = (float4*)Ws;
#pragma unroll
    for (int i = 0; i < DF * DF / 4 / 256; ++i)
        Ws4[i * 256 + tid] = W4[i * 256 + tid];

    // stage lrelu(X) tile: 32*128 floats = 1024 float4, 4 iters
    const float4* X4 = (const float4*)X;
    float4* Xs4 = (float4*)Xs;
#pragma unroll
    for (int i = 0; i < RPB * DF / 4 / 256; ++i) {
        int idx = i * 256 + tid;            // float4 index within tile
        int r = idx >> 5;                   // row in tile (128 floats = 32 float4 per row)
        int rowg = min(row_base + r, n - 1);
        float4 xv = X4[(size_t)rowg * (DF / 4) + (idx & 31)];
        xv.x = xv.x > 0.f ? xv.x : NSLOPE * xv.x;
        xv.y = xv.y > 0.f ? xv.y : NSLOPE * xv.y;
        xv.z = xv.z > 0.f ? xv.z : NSLOPE * xv.z;
        xv.w = xv.w > 0.f ? xv.w : NSLOPE * xv.w;
        Xs4[idx] = xv;
    }
    __syncthreads();

    int cgi = tid & 31;         // col-group index (4 cols each)
    int rg = tid >> 5;          // row-group 0..7 (4 rows each)
    int r0 = rg * 4;            // first tile-row of this thread

    float4 acc[4] = {make_float4(0,0,0,0), make_float4(0,0,0,0),
                     make_float4(0,0,0,0), make_float4(0,0,0,0)};

#pragma unroll 8
    for (int k4 = 0; k4 < DF / 4; ++k4) {
        float4 xv[4];
#pragma unroll
        for (int r = 0; r < 4; ++r)
            xv[r] = Xs4[(r0 + r) * 32 + k4];          // broadcast within rowgroup
        float4 w0 = Ws4[(k4 * 4 + 0) * 32 + cgi];     // 32 lanes contiguous 512B
        float4 w1 = Ws4[(k4 * 4 + 1) * 32 + cgi];
        float4 w2 = Ws4[(k4 * 4 + 2) * 32 + cgi];
        float4 w3 = Ws4[(k4 * 4 + 3) * 32 + cgi];
#pragma unroll
        for (int r = 0; r < 4; ++r) {
            acc[r].x += xv[r].x * w0.x; acc[r].y += xv[r].x * w0.y;
            acc[r].z += xv[r].x * w0.z; acc[r].w += xv[r].x * w0.w;
            acc[r].x += xv[r].y * w1.x; acc[r].y += xv[r].y * w1.y;
            acc[r].z += xv[r].y * w1.z; acc[r].w += xv[r].y * w1.w;
            acc[r].x += xv[r].z * w2.x; acc[r].y += xv[r].z * w2.y;
            acc[r].z += xv[r].z * w2.z; acc[r].w += xv[r].z * w2.w;
            acc[r].x += xv[r].w * w3.x; acc[r].y += xv[r].w * w3.y;
            acc[r].z += xv[r].w * w3.z; acc[r].w += xv[r].w * w3.w;
        }
    }

#pragma unroll
    for (int r = 0; r < 4; ++r) {
        int row = row_base + r0 + r;
        if (row < n)
            *(float4*)(H + (size_t)row * DF + cgi * 4) = acc[r];
    }
}

// ---------------- aggregation: one wave64 per node ----------------
// out[v] = b + dinv[v]^2 * H[v] + sum_{e: dst=v} dinv[src]*dinv[v] * H[src]

__global__ __launch_bounds__(256) void agg_kernel(const float* __restrict__ H,
                                                  const float* __restrict__ dinv,
                                                  const int* __restrict__ rowstart,
                                                  const int* __restrict__ csr,
                                                  const float* __restrict__ b,
                                                  float* __restrict__ out, int n) {
    int v = (blockIdx.x * 256 + threadIdx.x) >> 6;
    int lane = threadIdx.x & 63;
    if (v >= n) return;
    float dv = dinv[v];
    const float2* H2 = (const float2*)H;
    float2 hv = H2[(size_t)v * 64 + lane];
    float2 bb = ((const float2*)b)[lane];
    float sw = dv * dv;
    float2 acc;
    acc.x = hv.x * sw + bb.x;
    acc.y = hv.y * sw + bb.y;
    int j0 = rowstart[v], j1 = rowstart[v + 1];
    for (int j = j0; j < j1; ++j) {
        int s = csr[j];
        float w = dinv[s] * dv;
        float2 hs = H2[(size_t)s * 64 + lane];
        acc.x += hs.x * w;
        acc.y += hs.y * w;
    }
    ((float2*)out)[(size_t)v * 64 + lane] = acc;
}

extern "C" void kernel_launch(void* const* d_in, const int* in_sizes, int n_in,
                              void* d_out, int out_size, void* d_ws, size_t ws_size,
                              hipStream_t stream) {
    const float* x = (const float*)d_in[0];
    const int* ei = (const int*)d_in[1];
    const float* W1 = (const float*)d_in[2];
    const float* b1 = (const float*)d_in[3];
    const float* W2 = (const float*)d_in[4];
    const float* b2 = (const float*)d_in[5];
    const float* W3 = (const float*)d_in[6];
    const float* b3 = (const float*)d_in[7];
    float* out = (float*)d_out;

    const int N = in_sizes[0] / DF;
    const int E = in_sizes[1] / 2;

    char* ws = (char*)d_ws;
    size_t off = 0;
    auto alloc = [&](size_t bytes) {
        size_t o = off;
        off = (off + bytes + 15) & ~(size_t)15;
        return o;
    };
    int* cnt      = (int*)(ws + alloc((size_t)N * 4));
    int* cursor   = (int*)(ws + alloc((size_t)N * 4));
    float* dinv   = (float*)(ws + alloc((size_t)N * 4));
    int* rowstart = (int*)(ws + alloc((size_t)(N + 1) * 4));
    int* csr      = (int*)(ws + alloc((size_t)E * 4));
    float* H      = (float*)(ws + alloc((size_t)N * DF * 4));

    // zero cnt + cursor (adjacent at the front of ws)
    hipMemsetAsync(ws, 0, (size_t)N * 8, stream);

    int eb = (E + 255) / 256;
    count_kernel<<<eb, 256, 0, stream>>>(ei, cnt, E);
    scan_kernel<<<1, 1024, 0, stream>>>(cnt, rowstart, N);
    fill_kernel<<<eb, 256, 0, stream>>>(ei, rowstart, cursor, csr, E);
    dinv_kernel<<<(N + 255) / 256, 256, 0, stream>>>(cnt, dinv, N);

    int gemm_blocks = (N + RPB - 1) / RPB;
    int agg_blocks = (N * 64 + 255) / 256;

    // layer 1
    gemm_lrelu<<<gemm_blocks, 256, 0, stream>>>(x, W1, H, N);
    agg_kernel<<<agg_blocks, 256, 0, stream>>>(H, dinv, rowstart, csr, b1, out, N);
    // layer 2
    gemm_lrelu<<<gemm_blocks, 256, 0, stream>>>(out, W2, H, N);
    agg_kernel<<<agg_blocks, 256, 0, stream>>>(H, dinv, rowstart, csr, b2, out, N);
    // layer 3
    gemm_lrelu<<<gemm_blocks, 256, 0, stream>>>(out, W3, H, N);
    agg_kernel<<<agg_blocks, 256, 0, stream>>>(H, dinv, rowstart, csr, b3, out, N);
}

// Round 4
// 527.342 us; speedup vs baseline: 2.1649x; 1.3682x over previous
//
#include <hip/hip_runtime.h>

#define NSLOPE 0.01f
#define DF 128  // feature dim
#define RPB 32  // rows per block in gemm
#define SB 256  // scan blocks
#define ST 256  // scan threads

// ---------------- CSR build ----------------
// edge_index arrives as int32 (harness converts all integer inputs to int32).

__global__ __launch_bounds__(256) void count_kernel(const int* __restrict__ ei,
                                                    int* __restrict__ cnt, int E) {
    int e = blockIdx.x * 256 + threadIdx.x;
    if (e < E) atomicAdd(&cnt[ei[E + e]], 1);
}

// two-level scan: 256 blocks, each handles ceil(n/256) counters
__global__ __launch_bounds__(ST) void scan_part(const int* __restrict__ cnt,
                                                int* __restrict__ bsum, int n) {
    int chunk = (n + SB - 1) / SB;
    int start = blockIdx.x * chunk;
    int end = min(start + chunk, n);
    int s = 0;
    for (int i = start + (int)threadIdx.x; i < end; i += ST) s += cnt[i];
#pragma unroll
    for (int off = 32; off > 0; off >>= 1) s += __shfl_down(s, off, 64);
    __shared__ int wsum[ST / 64];
    if ((threadIdx.x & 63) == 0) wsum[threadIdx.x >> 6] = s;
    __syncthreads();
    if (threadIdx.x == 0) {
        int t = 0;
#pragma unroll
        for (int w = 0; w < ST / 64; ++w) t += wsum[w];
        bsum[blockIdx.x] = t;
    }
}

__global__ __launch_bounds__(ST) void scan_write(const int* __restrict__ cnt,
                                                 const int* __restrict__ bsum,
                                                 int* __restrict__ rowstart, int n) {
    int b = blockIdx.x;
    int t = threadIdx.x;
    // block offset = sum_{j<b} bsum[j]
    int v = (t < b) ? bsum[t] : 0;
#pragma unroll
    for (int off = 32; off > 0; off >>= 1) v += __shfl_down(v, off, 64);
    __shared__ int wsum[ST / 64];
    __shared__ int blockoff;
    if ((t & 63) == 0) wsum[t >> 6] = v;
    __syncthreads();
    if (t == 0) {
        int s = 0;
#pragma unroll
        for (int w = 0; w < ST / 64; ++w) s += wsum[w];
        blockoff = s;
    }
    // per-thread local sums over contiguous sub-chunks
    int chunk = (n + SB - 1) / SB;
    int start = b * chunk;
    int end = min(start + chunk, n);
    int pt = (chunk + ST - 1) / ST;
    int ts = start + t * pt;
    int te = min(ts + pt, end);
    int ls = 0;
    for (int i = ts; i < te; ++i) ls += cnt[i];
    // inclusive scan of per-thread sums
    __shared__ int ss[ST];
    ss[t] = ls;
    __syncthreads();
    for (int off = 1; off < ST; off <<= 1) {
        int vv = (t >= off) ? ss[t - off] : 0;
        __syncthreads();
        ss[t] += vv;
        __syncthreads();
    }
    int run = blockoff + (t == 0 ? 0 : ss[t - 1]);
    for (int i = ts; i < te; ++i) { rowstart[i] = run; run += cnt[i]; }
    if (b == SB - 1 && t == ST - 1) rowstart[n] = blockoff + ss[ST - 1];
}

__global__ __launch_bounds__(256) void fill_kernel(const int* __restrict__ ei,
                                                   const int* __restrict__ rowstart,
                                                   int* __restrict__ cursor,
                                                   int* __restrict__ csr, int E) {
    int e = blockIdx.x * 256 + threadIdx.x;
    if (e < E) {
        int d = ei[E + e];
        int pos = atomicAdd(&cursor[d], 1);
        csr[rowstart[d] + pos] = ei[e];
    }
}

__global__ __launch_bounds__(256) void dinv_kernel(const int* __restrict__ cnt,
                                                   float* __restrict__ dinv, int n) {
    int v = blockIdx.x * 256 + threadIdx.x;
    if (v < n) dinv[v] = rsqrtf((float)(cnt[v] + 1));  // +1 self loop
}

// ---------------- fused LeakyReLU + GEMM ----------------
// Block: 32 rows. W (64KB) + lrelu(X) tile (16KB) staged in LDS.
// Thread: 4 rows x 4 cols register tile.

__global__ __launch_bounds__(256) void gemm_lrelu(const float* __restrict__ X,
                                                  const float* __restrict__ W,
                                                  float* __restrict__ H, int n) {
    __shared__ float Ws[DF * DF];    // 64 KB
    __shared__ float Xs[RPB * DF];   // 16 KB

    int tid = threadIdx.x;
    int row_base = blockIdx.x * RPB;

    const float4* W4 = (const float4*)W;
    float4* Ws4 = (float4*)Ws;
#pragma unroll
    for (int i = 0; i < DF * DF / 4 / 256; ++i)
        Ws4[i * 256 + tid] = W4[i * 256 + tid];

    const float4* X4 = (const float4*)X;
    float4* Xs4 = (float4*)Xs;
#pragma unroll
    for (int i = 0; i < RPB * DF / 4 / 256; ++i) {
        int idx = i * 256 + tid;
        int r = idx >> 5;
        int rowg = min(row_base + r, n - 1);
        float4 xv = X4[(size_t)rowg * (DF / 4) + (idx & 31)];
        xv.x = xv.x > 0.f ? xv.x : NSLOPE * xv.x;
        xv.y = xv.y > 0.f ? xv.y : NSLOPE * xv.y;
        xv.z = xv.z > 0.f ? xv.z : NSLOPE * xv.z;
        xv.w = xv.w > 0.f ? xv.w : NSLOPE * xv.w;
        Xs4[idx] = xv;
    }
    __syncthreads();

    int cgi = tid & 31;
    int rg = tid >> 5;
    int r0 = rg * 4;

    float4 acc[4] = {make_float4(0,0,0,0), make_float4(0,0,0,0),
                     make_float4(0,0,0,0), make_float4(0,0,0,0)};

#pragma unroll 8
    for (int k4 = 0; k4 < DF / 4; ++k4) {
        float4 xv[4];
#pragma unroll
        for (int r = 0; r < 4; ++r)
            xv[r] = Xs4[(r0 + r) * 32 + k4];
        float4 w0 = Ws4[(k4 * 4 + 0) * 32 + cgi];
        float4 w1 = Ws4[(k4 * 4 + 1) * 32 + cgi];
        float4 w2 = Ws4[(k4 * 4 + 2) * 32 + cgi];
        float4 w3 = Ws4[(k4 * 4 + 3) * 32 + cgi];
#pragma unroll
        for (int r = 0; r < 4; ++r) {
            acc[r].x += xv[r].x * w0.x; acc[r].y += xv[r].x * w0.y;
            acc[r].z += xv[r].x * w0.z; acc[r].w += xv[r].x * w0.w;
            acc[r].x += xv[r].y * w1.x; acc[r].y += xv[r].y * w1.y;
            acc[r].z += xv[r].y * w1.z; acc[r].w += xv[r].y * w1.w;
            acc[r].x += xv[r].z * w2.x; acc[r].y += xv[r].z * w2.y;
            acc[r].z += xv[r].z * w2.z; acc[r].w += xv[r].z * w2.w;
            acc[r].x += xv[r].w * w3.x; acc[r].y += xv[r].w * w3.y;
            acc[r].z += xv[r].w * w3.z; acc[r].w += xv[r].w * w3.w;
        }
    }

#pragma unroll
    for (int r = 0; r < 4; ++r) {
        int row = row_base + r0 + r;
        if (row < n)
            *(float4*)(H + (size_t)row * DF + cgi * 4) = acc[r];
    }
}

// ---------------- aggregation: one wave64 per node, 4-way edge ILP ----------

__global__ __launch_bounds__(256) void agg_kernel(const float* __restrict__ H,
                                                  const float* __restrict__ dinv,
                                                  const int* __restrict__ rowstart,
                                                  const int* __restrict__ csr,
                                                  const float* __restrict__ b,
                                                  float* __restrict__ out, int n) {
    int v = (blockIdx.x * 256 + threadIdx.x) >> 6;
    int lane = threadIdx.x & 63;
    if (v >= n) return;
    float dv = dinv[v];
    const float2* H2 = (const float2*)H;
    float2 hv = H2[(size_t)v * 64 + lane];
    float2 bb = ((const float2*)b)[lane];
    float sw = dv * dv;
    float2 a0, a1, a2, a3;
    a0.x = hv.x * sw + bb.x;
    a0.y = hv.y * sw + bb.y;
    a1 = make_float2(0.f, 0.f);
    a2 = make_float2(0.f, 0.f);
    a3 = make_float2(0.f, 0.f);
    int j0 = rowstart[v], j1 = rowstart[v + 1];
    int j = j0;
    for (; j + 3 < j1; j += 4) {
        int s0 = csr[j + 0];
        int s1 = csr[j + 1];
        int s2 = csr[j + 2];
        int s3 = csr[j + 3];
        float w0 = dinv[s0] * dv;
        float w1 = dinv[s1] * dv;
        float w2 = dinv[s2] * dv;
        float w3 = dinv[s3] * dv;
        float2 h0 = H2[(size_t)s0 * 64 + lane];
        float2 h1 = H2[(size_t)s1 * 64 + lane];
        float2 h2 = H2[(size_t)s2 * 64 + lane];
        float2 h3 = H2[(size_t)s3 * 64 + lane];
        a0.x += h0.x * w0; a0.y += h0.y * w0;
        a1.x += h1.x * w1; a1.y += h1.y * w1;
        a2.x += h2.x * w2; a2.y += h2.y * w2;
        a3.x += h3.x * w3; a3.y += h3.y * w3;
    }
    for (; j < j1; ++j) {
        int s = csr[j];
        float w = dinv[s] * dv;
        float2 hs = H2[(size_t)s * 64 + lane];
        a0.x += hs.x * w;
        a0.y += hs.y * w;
    }
    float2 acc;
    acc.x = (a0.x + a1.x) + (a2.x + a3.x);
    acc.y = (a0.y + a1.y) + (a2.y + a3.y);
    ((float2*)out)[(size_t)v * 64 + lane] = acc;
}

extern "C" void kernel_launch(void* const* d_in, const int* in_sizes, int n_in,
                              void* d_out, int out_size, void* d_ws, size_t ws_size,
                              hipStream_t stream) {
    const float* x = (const float*)d_in[0];
    const int* ei = (const int*)d_in[1];
    const float* W1 = (const float*)d_in[2];
    const float* b1 = (const float*)d_in[3];
    const float* W2 = (const float*)d_in[4];
    const float* b2 = (const float*)d_in[5];
    const float* W3 = (const float*)d_in[6];
    const float* b3 = (const float*)d_in[7];
    float* out = (float*)d_out;

    const int N = in_sizes[0] / DF;
    const int E = in_sizes[1] / 2;

    char* ws = (char*)d_ws;
    size_t off = 0;
    auto alloc = [&](size_t bytes) {
        size_t o = off;
        off = (off + bytes + 15) & ~(size_t)15;
        return o;
    };
    int* cnt      = (int*)(ws + alloc((size_t)N * 4));
    int* cursor   = (int*)(ws + alloc((size_t)N * 4));
    float* dinv   = (float*)(ws + alloc((size_t)N * 4));
    int* rowstart = (int*)(ws + alloc((size_t)(N + 1) * 4));
    int* bsum     = (int*)(ws + alloc((size_t)SB * 4));
    int* csr      = (int*)(ws + alloc((size_t)E * 4));
    float* H      = (float*)(ws + alloc((size_t)N * DF * 4));

    // zero cnt + cursor (adjacent at the front of ws)
    hipMemsetAsync(ws, 0, (size_t)N * 8, stream);

    int eb = (E + 255) / 256;
    count_kernel<<<eb, 256, 0, stream>>>(ei, cnt, E);
    scan_part<<<SB, ST, 0, stream>>>(cnt, bsum, N);
    scan_write<<<SB, ST, 0, stream>>>(cnt, bsum, rowstart, N);
    fill_kernel<<<eb, 256, 0, stream>>>(ei, rowstart, cursor, csr, E);
    dinv_kernel<<<(N + 255) / 256, 256, 0, stream>>>(cnt, dinv, N);

    int gemm_blocks = (N + RPB - 1) / RPB;
    int agg_blocks = (N * 64 + 255) / 256;

    // layer 1
    gemm_lrelu<<<gemm_blocks, 256, 0, stream>>>(x, W1, H, N);
    agg_kernel<<<agg_blocks, 256, 0, stream>>>(H, dinv, rowstart, csr, b1, out, N);
    // layer 2
    gemm_lrelu<<<gemm_blocks, 256, 0, stream>>>(out, W2, H, N);
    agg_kernel<<<agg_blocks, 256, 0, stream>>>(H, dinv, rowstart, csr, b2, out, N);
    // layer 3
    gemm_lrelu<<<gemm_blocks, 256, 0, stream>>>(out, W3, H, N);
    agg_kernel<<<agg_blocks, 256, 0, stream>>>(H, dinv, rowstart, csr, b3, out, N);
}

// Round 5
// 495.086 us; speedup vs baseline: 2.3060x; 1.0652x over previous
//
#include <hip/hip_runtime.h>

#define NSLOPE 0.01f
#define DF 128  // feature dim
#define GR 64   // rows per block in gemm
#define SB 256  // scan blocks
#define ST 256  // scan threads

// ---------------- CSR build ----------------
// edge_index arrives as int32 (harness converts all integer inputs to int32).

__global__ __launch_bounds__(256) void count_kernel(const int* __restrict__ ei,
                                                    int* __restrict__ cnt, int E) {
    int e = blockIdx.x * 256 + threadIdx.x;
    if (e < E) atomicAdd(&cnt[ei[E + e]], 1);
}

// two-level scan: 256 blocks, each handles ceil(n/256) counters
__global__ __launch_bounds__(ST) void scan_part(const int* __restrict__ cnt,
                                                int* __restrict__ bsum, int n) {
    int chunk = (n + SB - 1) / SB;
    int start = blockIdx.x * chunk;
    int end = min(start + chunk, n);
    int s = 0;
    for (int i = start + (int)threadIdx.x; i < end; i += ST) s += cnt[i];
#pragma unroll
    for (int off = 32; off > 0; off >>= 1) s += __shfl_down(s, off, 64);
    __shared__ int wsum[ST / 64];
    if ((threadIdx.x & 63) == 0) wsum[threadIdx.x >> 6] = s;
    __syncthreads();
    if (threadIdx.x == 0) {
        int t = 0;
#pragma unroll
        for (int w = 0; w < ST / 64; ++w) t += wsum[w];
        bsum[blockIdx.x] = t;
    }
}

__global__ __launch_bounds__(ST) void scan_write(const int* __restrict__ cnt,
                                                 const int* __restrict__ bsum,
                                                 int* __restrict__ rowstart, int n) {
    int b = blockIdx.x;
    int t = threadIdx.x;
    int v = (t < b) ? bsum[t] : 0;
#pragma unroll
    for (int off = 32; off > 0; off >>= 1) v += __shfl_down(v, off, 64);
    __shared__ int wsum[ST / 64];
    __shared__ int blockoff;
    if ((t & 63) == 0) wsum[t >> 6] = v;
    __syncthreads();
    if (t == 0) {
        int s = 0;
#pragma unroll
        for (int w = 0; w < ST / 64; ++w) s += wsum[w];
        blockoff = s;
    }
    int chunk = (n + SB - 1) / SB;
    int start = b * chunk;
    int end = min(start + chunk, n);
    int pt = (chunk + ST - 1) / ST;
    int ts = start + t * pt;
    int te = min(ts + pt, end);
    int ls = 0;
    for (int i = ts; i < te; ++i) ls += cnt[i];
    __shared__ int ss[ST];
    ss[t] = ls;
    __syncthreads();
    for (int off = 1; off < ST; off <<= 1) {
        int vv = (t >= off) ? ss[t - off] : 0;
        __syncthreads();
        ss[t] += vv;
        __syncthreads();
    }
    int run = blockoff + (t == 0 ? 0 : ss[t - 1]);
    for (int i = ts; i < te; ++i) { rowstart[i] = run; run += cnt[i]; }
    if (b == SB - 1 && t == ST - 1) rowstart[n] = blockoff + ss[ST - 1];
}

__global__ __launch_bounds__(256) void fill_kernel(const int* __restrict__ ei,
                                                   const int* __restrict__ rowstart,
                                                   int* __restrict__ cursor,
                                                   int* __restrict__ csr, int E) {
    int e = blockIdx.x * 256 + threadIdx.x;
    if (e < E) {
        int d = ei[E + e];
        int pos = atomicAdd(&cursor[d], 1);
        csr[rowstart[d] + pos] = ei[e];
    }
}

__global__ __launch_bounds__(256) void dinv_kernel(const int* __restrict__ cnt,
                                                   float* __restrict__ dinv, int n) {
    int v = blockIdx.x * 256 + threadIdx.x;
    if (v < n) dinv[v] = rsqrtf((float)(cnt[v] + 1));  // +1 self loop
}

// ---------------- fused LeakyReLU + GEMM ----------------
// Block: 64 rows x 128 cols. Only lrelu(X) tile staged in LDS (32 KB);
// W read through L1/L2 (64 KB footprint, shared by all blocks).
// Thread: 8 rows x 4 cols register tile. 32 colgroups x 8 rowgroups.

__global__ __launch_bounds__(256) void gemm_lrelu(const float* __restrict__ X,
                                                  const float* __restrict__ W,
                                                  float* __restrict__ H, int n) {
    __shared__ float4 Xs4[GR * 32];   // 64 rows x 128 cols = 32 KB

    int tid = threadIdx.x;
    int row_base = blockIdx.x * GR;

    const float4* X4 = (const float4*)X;
#pragma unroll
    for (int i = 0; i < GR * 32 / 256; ++i) {   // 8 iters, coalesced
        int idx = i * 256 + tid;
        int r = idx >> 5;
        int rowg = min(row_base + r, n - 1);
        float4 xv = X4[(size_t)rowg * 32 + (idx & 31)];
        xv.x = xv.x > 0.f ? xv.x : NSLOPE * xv.x;
        xv.y = xv.y > 0.f ? xv.y : NSLOPE * xv.y;
        xv.z = xv.z > 0.f ? xv.z : NSLOPE * xv.z;
        xv.w = xv.w > 0.f ? xv.w : NSLOPE * xv.w;
        Xs4[idx] = xv;
    }
    __syncthreads();

    int cgi = tid & 31;          // col group (4 cols)
    int rg = tid >> 5;           // row group 0..7
    int r0 = rg * 8;             // 8 rows per thread

    const float4* W4 = (const float4*)W;
    float4 acc[8];
#pragma unroll
    for (int r = 0; r < 8; ++r) acc[r] = make_float4(0.f, 0.f, 0.f, 0.f);

#pragma unroll 4
    for (int k4 = 0; k4 < DF / 4; ++k4) {
        float4 w0 = W4[(k4 * 4 + 0) * 32 + cgi];   // L1-resident
        float4 w1 = W4[(k4 * 4 + 1) * 32 + cgi];
        float4 w2 = W4[(k4 * 4 + 2) * 32 + cgi];
        float4 w3 = W4[(k4 * 4 + 3) * 32 + cgi];
#pragma unroll
        for (int r = 0; r < 8; ++r) {
            float4 xv = Xs4[(r0 + r) * 32 + k4];   // LDS broadcast
            acc[r].x += xv.x * w0.x; acc[r].y += xv.x * w0.y;
            acc[r].z += xv.x * w0.z; acc[r].w += xv.x * w0.w;
            acc[r].x += xv.y * w1.x; acc[r].y += xv.y * w1.y;
            acc[r].z += xv.y * w1.z; acc[r].w += xv.y * w1.w;
            acc[r].x += xv.z * w2.x; acc[r].y += xv.z * w2.y;
            acc[r].z += xv.z * w2.z; acc[r].w += xv.z * w2.w;
            acc[r].x += xv.w * w3.x; acc[r].y += xv.w * w3.y;
            acc[r].z += xv.w * w3.z; acc[r].w += xv.w * w3.w;
        }
    }

#pragma unroll
    for (int r = 0; r < 8; ++r) {
        int row = row_base + r0 + r;
        if (row < n)
            *(float4*)(H + (size_t)row * DF + cgi * 4) = acc[r];
    }
}

// ---------------- aggregation: 2 nodes per wave, 32 lanes x float4 ----------
// out[v] = b + dinv[v]^2 * H[v] + sum_{e: dst=v} dinv[src]*dinv[v] * H[src]

__global__ __launch_bounds__(256) void agg_kernel(const float* __restrict__ H,
                                                  const float* __restrict__ dinv,
                                                  const int* __restrict__ rowstart,
                                                  const int* __restrict__ csr,
                                                  const float* __restrict__ b,
                                                  float* __restrict__ out, int n) {
    int g = blockIdx.x * 256 + threadIdx.x;
    int v = g >> 5;              // 32 lanes per node
    int lane = g & 31;           // float4 slot: 32*16B = 512B per node row
    if (v >= n) return;
    float dv = dinv[v];
    const float4* H4 = (const float4*)H;
    float4 hv = H4[(size_t)v * 32 + lane];
    float4 bb = ((const float4*)b)[lane];
    float sw = dv * dv;
    float4 a0, a1, a2, a3;
    a0.x = hv.x * sw + bb.x; a0.y = hv.y * sw + bb.y;
    a0.z = hv.z * sw + bb.z; a0.w = hv.w * sw + bb.w;
    a1 = make_float4(0.f, 0.f, 0.f, 0.f);
    a2 = make_float4(0.f, 0.f, 0.f, 0.f);
    a3 = make_float4(0.f, 0.f, 0.f, 0.f);
    int j0 = rowstart[v], j1 = rowstart[v + 1];
    int j = j0;
    for (; j + 3 < j1; j += 4) {
        int s0 = csr[j + 0];
        int s1 = csr[j + 1];
        int s2 = csr[j + 2];
        int s3 = csr[j + 3];
        float w0 = dinv[s0] * dv;
        float w1 = dinv[s1] * dv;
        float w2 = dinv[s2] * dv;
        float w3 = dinv[s3] * dv;
        float4 h0 = H4[(size_t)s0 * 32 + lane];
        float4 h1 = H4[(size_t)s1 * 32 + lane];
        float4 h2 = H4[(size_t)s2 * 32 + lane];
        float4 h3 = H4[(size_t)s3 * 32 + lane];
        a0.x += h0.x * w0; a0.y += h0.y * w0; a0.z += h0.z * w0; a0.w += h0.w * w0;
        a1.x += h1.x * w1; a1.y += h1.y * w1; a1.z += h1.z * w1; a1.w += h1.w * w1;
        a2.x += h2.x * w2; a2.y += h2.y * w2; a2.z += h2.z * w2; a2.w += h2.w * w2;
        a3.x += h3.x * w3; a3.y += h3.y * w3; a3.z += h3.z * w3; a3.w += h3.w * w3;
    }
    for (; j < j1; ++j) {
        int s = csr[j];
        float w = dinv[s] * dv;
        float4 hs = H4[(size_t)s * 32 + lane];
        a0.x += hs.x * w; a0.y += hs.y * w; a0.z += hs.z * w; a0.w += hs.w * w;
    }
    float4 acc;
    acc.x = (a0.x + a1.x) + (a2.x + a3.x);
    acc.y = (a0.y + a1.y) + (a2.y + a3.y);
    acc.z = (a0.z + a1.z) + (a2.z + a3.z);
    acc.w = (a0.w + a1.w) + (a2.w + a3.w);
    ((float4*)out)[(size_t)v * 32 + lane] = acc;
}

extern "C" void kernel_launch(void* const* d_in, const int* in_sizes, int n_in,
                              void* d_out, int out_size, void* d_ws, size_t ws_size,
                              hipStream_t stream) {
    const float* x = (const float*)d_in[0];
    const int* ei = (const int*)d_in[1];
    const float* W1 = (const float*)d_in[2];
    const float* b1 = (const float*)d_in[3];
    const float* W2 = (const float*)d_in[4];
    const float* b2 = (const float*)d_in[5];
    const float* W3 = (const float*)d_in[6];
    const float* b3 = (const float*)d_in[7];
    float* out = (float*)d_out;

    const int N = in_sizes[0] / DF;
    const int E = in_sizes[1] / 2;

    char* ws = (char*)d_ws;
    size_t off = 0;
    auto alloc = [&](size_t bytes) {
        size_t o = off;
        off = (off + bytes + 15) & ~(size_t)15;
        return o;
    };
    int* cnt      = (int*)(ws + alloc((size_t)N * 4));
    int* cursor   = (int*)(ws + alloc((size_t)N * 4));
    float* dinv   = (float*)(ws + alloc((size_t)N * 4));
    int* rowstart = (int*)(ws + alloc((size_t)(N + 1) * 4));
    int* bsum     = (int*)(ws + alloc((size_t)SB * 4));
    int* csr      = (int*)(ws + alloc((size_t)E * 4));
    float* H      = (float*)(ws + alloc((size_t)N * DF * 4));

    // zero cnt + cursor (adjacent at the front of ws)
    hipMemsetAsync(ws, 0, (size_t)N * 8, stream);

    int eb = (E + 255) / 256;
    count_kernel<<<eb, 256, 0, stream>>>(ei, cnt, E);
    scan_part<<<SB, ST, 0, stream>>>(cnt, bsum, N);
    scan_write<<<SB, ST, 0, stream>>>(cnt, bsum, rowstart, N);
    fill_kernel<<<eb, 256, 0, stream>>>(ei, rowstart, cursor, csr, E);
    dinv_kernel<<<(N + 255) / 256, 256, 0, stream>>>(cnt, dinv, N);

    int gemm_blocks = (N + GR - 1) / GR;
    int agg_blocks = (N * 32 + 255) / 256;

    // layer 1
    gemm_lrelu<<<gemm_blocks, 256, 0, stream>>>(x, W1, H, N);
    agg_kernel<<<agg_blocks, 256, 0, stream>>>(H, dinv, rowstart, csr, b1, out, N);
    // layer 2
    gemm_lrelu<<<gemm_blocks, 256, 0, stream>>>(out, W2, H, N);
    agg_kernel<<<agg_blocks, 256, 0, stream>>>(H, dinv, rowstart, csr, b2, out, N);
    // layer 3
    gemm_lrelu<<<gemm_blocks, 256, 0, stream>>>(out, W3, H, N);
    agg_kernel<<<agg_blocks, 256, 0, stream>>>(H, dinv, rowstart, csr, b3, out, N);
}

// Round 6
// 357.735 us; speedup vs baseline: 3.1914x; 1.3839x over previous
//
#include <hip/hip_runtime.h>

#define NSLOPE 0.01f
#define DF 128  // feature dim
#define SB 256  // scan blocks
#define ST 256  // scan threads

typedef __attribute__((ext_vector_type(8))) short short8v;   // 8 bf16 = 4 VGPR
typedef __attribute__((ext_vector_type(16))) float f32x16;   // MFMA 32x32 acc

static __device__ __forceinline__ float lrelu(float x) {
    return x > 0.f ? x : NSLOPE * x;
}
// fp32 -> bf16, round-to-nearest-even (values are finite)
static __device__ __forceinline__ short f2bf(float f) {
    unsigned u = __float_as_uint(f);
    unsigned r = (u + 0x7FFFu + ((u >> 16) & 1u)) >> 16;
    return (short)r;
}

// ---------------- CSR build ----------------

__global__ __launch_bounds__(256) void count_kernel(const int* __restrict__ ei,
                                                    int* __restrict__ cnt, int E) {
    int e = blockIdx.x * 256 + threadIdx.x;
    if (e < E) atomicAdd(&cnt[ei[E + e]], 1);
}

__global__ __launch_bounds__(ST) void scan_part(const int* __restrict__ cnt,
                                                int* __restrict__ bsum, int n) {
    int chunk = (n + SB - 1) / SB;
    int start = blockIdx.x * chunk;
    int end = min(start + chunk, n);
    int s = 0;
    for (int i = start + (int)threadIdx.x; i < end; i += ST) s += cnt[i];
#pragma unroll
    for (int off = 32; off > 0; off >>= 1) s += __shfl_down(s, off, 64);
    __shared__ int wsum[ST / 64];
    if ((threadIdx.x & 63) == 0) wsum[threadIdx.x >> 6] = s;
    __syncthreads();
    if (threadIdx.x == 0) {
        int t = 0;
#pragma unroll
        for (int w = 0; w < ST / 64; ++w) t += wsum[w];
        bsum[blockIdx.x] = t;
    }
}

__global__ __launch_bounds__(ST) void scan_write(const int* __restrict__ cnt,
                                                 const int* __restrict__ bsum,
                                                 int* __restrict__ rowstart, int n) {
    int b = blockIdx.x;
    int t = threadIdx.x;
    int v = (t < b) ? bsum[t] : 0;
#pragma unroll
    for (int off = 32; off > 0; off >>= 1) v += __shfl_down(v, off, 64);
    __shared__ int wsum[ST / 64];
    __shared__ int blockoff;
    if ((t & 63) == 0) wsum[t >> 6] = v;
    __syncthreads();
    if (t == 0) {
        int s = 0;
#pragma unroll
        for (int w = 0; w < ST / 64; ++w) s += wsum[w];
        blockoff = s;
    }
    int chunk = (n + SB - 1) / SB;
    int start = b * chunk;
    int end = min(start + chunk, n);
    int pt = (chunk + ST - 1) / ST;
    int ts = start + t * pt;
    int te = min(ts + pt, end);
    int ls = 0;
    for (int i = ts; i < te; ++i) ls += cnt[i];
    __shared__ int ss[ST];
    ss[t] = ls;
    __syncthreads();
    for (int off = 1; off < ST; off <<= 1) {
        int vv = (t >= off) ? ss[t - off] : 0;
        __syncthreads();
        ss[t] += vv;
        __syncthreads();
    }
    int run = blockoff + (t == 0 ? 0 : ss[t - 1]);
    for (int i = ts; i < te; ++i) { rowstart[i] = run; run += cnt[i]; }
    if (b == SB - 1 && t == ST - 1) rowstart[n] = blockoff + ss[ST - 1];
}

__global__ __launch_bounds__(256) void fill_kernel(const int* __restrict__ ei,
                                                   const int* __restrict__ rowstart,
                                                   int* __restrict__ cursor,
                                                   int* __restrict__ csr, int E) {
    int e = blockIdx.x * 256 + threadIdx.x;
    if (e < E) {
        int d = ei[E + e];
        int pos = atomicAdd(&cursor[d], 1);
        csr[rowstart[d] + pos] = ei[e];
    }
}

__global__ __launch_bounds__(256) void dinv_kernel(const int* __restrict__ cnt,
                                                   float* __restrict__ dinv, int n) {
    int v = blockIdx.x * 256 + threadIdx.x;
    if (v < n) dinv[v] = rsqrtf((float)(cnt[v] + 1));  // +1 self loop
}

// ---------------- weight prep: Wt[n][k] = bf16(W[k][n]) ----------------

__global__ __launch_bounds__(256) void w_prep(const float* __restrict__ W1,
                                              const float* __restrict__ W2,
                                              const float* __restrict__ W3,
                                              short* __restrict__ Wt1,
                                              short* __restrict__ Wt2,
                                              short* __restrict__ Wt3) {
    const float* W = blockIdx.y == 0 ? W1 : (blockIdx.y == 1 ? W2 : W3);
    short* Wt = blockIdx.y == 0 ? Wt1 : (blockIdx.y == 1 ? Wt2 : Wt3);
    int idx = blockIdx.x * 256 + threadIdx.x;   // 16384 elems
    int k = idx >> 7, nn = idx & 127;
    Wt[nn * 128 + k] = f2bf(W[idx]);            // coalesced read, scatter write (tiny)
}

// ---------------- fused LeakyReLU + GEMM via MFMA (bf16 in, f32 acc) -------
// H[row][c] = sum_k lrelu(X[row][k]) * W[k][c]
// Block: 128 rows x 128 cols, 4 waves; wave = 32 rows x 4 col-tiles.
// LDS: lrelu(X) as bf16 [128][128] + Wt bf16 [128][128], both in 16B chunks
// XOR-swizzled: chunk(row, slot) -> row*16 + (slot ^ (row & 15)).

__global__ __launch_bounds__(256) void gemm_mfma(const float* __restrict__ X,
                                                 const short* __restrict__ Wt,
                                                 float* __restrict__ H, int n) {
    __shared__ short8v XsC[128 * 16];   // 32 KB
    __shared__ short8v WsC[128 * 16];   // 32 KB

    int tid = threadIdx.x;
    int rowbase = blockIdx.x * 128;

    // stage lrelu(X) -> bf16 chunks
    const float4* X4 = (const float4*)X;
#pragma unroll
    for (int i = 0; i < 8; ++i) {
        int idx = i * 256 + tid;              // 2048 chunks
        int r = idx >> 4, s = idx & 15;
        int rowg = min(rowbase + r, n - 1);
        float4 g0 = X4[(size_t)rowg * 32 + s * 2];
        float4 g1 = X4[(size_t)rowg * 32 + s * 2 + 1];
        short8v v;
        v[0] = f2bf(lrelu(g0.x)); v[1] = f2bf(lrelu(g0.y));
        v[2] = f2bf(lrelu(g0.z)); v[3] = f2bf(lrelu(g0.w));
        v[4] = f2bf(lrelu(g1.x)); v[5] = f2bf(lrelu(g1.y));
        v[6] = f2bf(lrelu(g1.z)); v[7] = f2bf(lrelu(g1.w));
        XsC[r * 16 + (s ^ (r & 15))] = v;
    }
    // stage Wt (already bf16, row-major [n][k])
    const short8v* Wt8 = (const short8v*)Wt;
#pragma unroll
    for (int i = 0; i < 8; ++i) {
        int idx = i * 256 + tid;
        int r = idx >> 4, s = idx & 15;
        WsC[r * 16 + (s ^ (r & 15))] = Wt8[idx];
    }
    __syncthreads();

    int w = tid >> 6;            // wave 0..3 -> rows 32w..32w+31
    int l = tid & 63;
    int ln = l & 31;
    int half = l >> 5;
    int arow = 32 * w + ln;
    int rsw = ln & 15;           // row-swizzle term (same for arow and n-rows)

    f32x16 acc[4];
#pragma unroll
    for (int c = 0; c < 4; ++c)
#pragma unroll
        for (int r = 0; r < 16; ++r) acc[c][r] = 0.f;

#pragma unroll
    for (int ks = 0; ks < 8; ++ks) {         // K = 128, 16 per step
        int sw = (ks * 2 + half) ^ rsw;
        short8v a = XsC[arow * 16 + sw];
        short8v b0 = WsC[(0 * 32 + ln) * 16 + sw];
        short8v b1 = WsC[(1 * 32 + ln) * 16 + sw];
        short8v b2 = WsC[(2 * 32 + ln) * 16 + sw];
        short8v b3 = WsC[(3 * 32 + ln) * 16 + sw];
        acc[0] = __builtin_amdgcn_mfma_f32_32x32x16_bf16(a, b0, acc[0], 0, 0, 0);
        acc[1] = __builtin_amdgcn_mfma_f32_32x32x16_bf16(a, b1, acc[1], 0, 0, 0);
        acc[2] = __builtin_amdgcn_mfma_f32_32x32x16_bf16(a, b2, acc[2], 0, 0, 0);
        acc[3] = __builtin_amdgcn_mfma_f32_32x32x16_bf16(a, b3, acc[3], 0, 0, 0);
    }

    // C/D layout (m74/m101 verified): col = lane&31, row = (r&3)+8*(r>>2)+4*half
#pragma unroll
    for (int c = 0; c < 4; ++c) {
#pragma unroll
        for (int r = 0; r < 16; ++r) {
            int rowt = (r & 3) + 8 * (r >> 2) + 4 * half;
            int grow = rowbase + 32 * w + rowt;
            if (grow < n)
                H[(size_t)grow * DF + c * 32 + ln] = acc[c][r];
        }
    }
}

// ---------------- aggregation: 2 nodes per wave, 32 lanes x float4 ----------
// out[v] = b + dinv[v]^2 * H[v] + sum_{e: dst=v} dinv[src]*dinv[v] * H[src]

__global__ __launch_bounds__(256) void agg_kernel(const float* __restrict__ H,
                                                  const float* __restrict__ dinv,
                                                  const int* __restrict__ rowstart,
                                                  const int* __restrict__ csr,
                                                  const float* __restrict__ b,
                                                  float* __restrict__ out, int n) {
    int g = blockIdx.x * 256 + threadIdx.x;
    int v = g >> 5;
    int lane = g & 31;
    if (v >= n) return;
    float dv = dinv[v];
    const float4* H4 = (const float4*)H;
    float4 hv = H4[(size_t)v * 32 + lane];
    float4 bb = ((const float4*)b)[lane];
    float sw = dv * dv;
    float4 a0, a1, a2, a3;
    a0.x = hv.x * sw + bb.x; a0.y = hv.y * sw + bb.y;
    a0.z = hv.z * sw + bb.z; a0.w = hv.w * sw + bb.w;
    a1 = make_float4(0.f, 0.f, 0.f, 0.f);
    a2 = make_float4(0.f, 0.f, 0.f, 0.f);
    a3 = make_float4(0.f, 0.f, 0.f, 0.f);
    int j0 = rowstart[v], j1 = rowstart[v + 1];
    int j = j0;
    for (; j + 3 < j1; j += 4) {
        int s0 = csr[j + 0];
        int s1 = csr[j + 1];
        int s2 = csr[j + 2];
        int s3 = csr[j + 3];
        float w0 = dinv[s0] * dv;
        float w1 = dinv[s1] * dv;
        float w2 = dinv[s2] * dv;
        float w3 = dinv[s3] * dv;
        float4 h0 = H4[(size_t)s0 * 32 + lane];
        float4 h1 = H4[(size_t)s1 * 32 + lane];
        float4 h2 = H4[(size_t)s2 * 32 + lane];
        float4 h3 = H4[(size_t)s3 * 32 + lane];
        a0.x += h0.x * w0; a0.y += h0.y * w0; a0.z += h0.z * w0; a0.w += h0.w * w0;
        a1.x += h1.x * w1; a1.y += h1.y * w1; a1.z += h1.z * w1; a1.w += h1.w * w1;
        a2.x += h2.x * w2; a2.y += h2.y * w2; a2.z += h2.z * w2; a2.w += h2.w * w2;
        a3.x += h3.x * w3; a3.y += h3.y * w3; a3.z += h3.z * w3; a3.w += h3.w * w3;
    }
    for (; j < j1; ++j) {
        int s = csr[j];
        float w = dinv[s] * dv;
        float4 hs = H4[(size_t)s * 32 + lane];
        a0.x += hs.x * w; a0.y += hs.y * w; a0.z += hs.z * w; a0.w += hs.w * w;
    }
    float4 acc;
    acc.x = (a0.x + a1.x) + (a2.x + a3.x);
    acc.y = (a0.y + a1.y) + (a2.y + a3.y);
    acc.z = (a0.z + a1.z) + (a2.z + a3.z);
    acc.w = (a0.w + a1.w) + (a2.w + a3.w);
    ((float4*)out)[(size_t)v * 32 + lane] = acc;
}

extern "C" void kernel_launch(void* const* d_in, const int* in_sizes, int n_in,
                              void* d_out, int out_size, void* d_ws, size_t ws_size,
                              hipStream_t stream) {
    const float* x = (const float*)d_in[0];
    const int* ei = (const int*)d_in[1];
    const float* W1 = (const float*)d_in[2];
    const float* b1 = (const float*)d_in[3];
    const float* W2 = (const float*)d_in[4];
    const float* b2 = (const float*)d_in[5];
    const float* W3 = (const float*)d_in[6];
    const float* b3 = (const float*)d_in[7];
    float* out = (float*)d_out;

    const int N = in_sizes[0] / DF;
    const int E = in_sizes[1] / 2;

    char* ws = (char*)d_ws;
    size_t off = 0;
    auto alloc = [&](size_t bytes) {
        size_t o = off;
        off = (off + bytes + 15) & ~(size_t)15;
        return o;
    };
    int* cnt      = (int*)(ws + alloc((size_t)N * 4));
    int* cursor   = (int*)(ws + alloc((size_t)N * 4));
    float* dinv   = (float*)(ws + alloc((size_t)N * 4));
    int* rowstart = (int*)(ws + alloc((size_t)(N + 1) * 4));
    int* bsum     = (int*)(ws + alloc((size_t)SB * 4));
    int* csr      = (int*)(ws + alloc((size_t)E * 4));
    float* H      = (float*)(ws + alloc((size_t)N * DF * 4));
    short* Wt1    = (short*)(ws + alloc((size_t)DF * DF * 2));
    short* Wt2    = (short*)(ws + alloc((size_t)DF * DF * 2));
    short* Wt3    = (short*)(ws + alloc((size_t)DF * DF * 2));

    // zero cnt + cursor (adjacent at the front of ws)
    hipMemsetAsync(ws, 0, (size_t)N * 8, stream);

    w_prep<<<dim3(DF * DF / 256, 3), 256, 0, stream>>>(W1, W2, W3, Wt1, Wt2, Wt3);

    int eb = (E + 255) / 256;
    count_kernel<<<eb, 256, 0, stream>>>(ei, cnt, E);
    scan_part<<<SB, ST, 0, stream>>>(cnt, bsum, N);
    scan_write<<<SB, ST, 0, stream>>>(cnt, bsum, rowstart, N);
    fill_kernel<<<eb, 256, 0, stream>>>(ei, rowstart, cursor, csr, E);
    dinv_kernel<<<(N + 255) / 256, 256, 0, stream>>>(cnt, dinv, N);

    int gemm_blocks = (N + 127) / 128;
    int agg_blocks = (N * 32 + 255) / 256;

    // layer 1
    gemm_mfma<<<gemm_blocks, 256, 0, stream>>>(x, Wt1, H, N);
    agg_kernel<<<agg_blocks, 256, 0, stream>>>(H, dinv, rowstart, csr, b1, out, N);
    // layer 2
    gemm_mfma<<<gemm_blocks, 256, 0, stream>>>(out, Wt2, H, N);
    agg_kernel<<<agg_blocks, 256, 0, stream>>>(H, dinv, rowstart, csr, b2, out, N);
    // layer 3
    gemm_mfma<<<gemm_blocks, 256, 0, stream>>>(out, Wt3, H, N);
    agg_kernel<<<agg_blocks, 256, 0, stream>>>(H, dinv, rowstart, csr, b3, out, N);
}

// Round 7
// 312.188 us; speedup vs baseline: 3.6570x; 1.1459x over previous
//
#include <hip/hip_runtime.h>

#define NSLOPE 0.01f
#define DF 128  // feature dim
#define SB 256  // scan blocks
#define ST 256  // scan threads

typedef __attribute__((ext_vector_type(8))) short short8v;   // 8 bf16 = 4 VGPR
typedef __attribute__((ext_vector_type(16))) float f32x16;   // MFMA 32x32 acc

static __device__ __forceinline__ float lrelu(float x) {
    return x > 0.f ? x : NSLOPE * x;
}
// fp32 -> bf16, round-to-nearest-even (values are finite)
static __device__ __forceinline__ unsigned short f2bf(float f) {
    unsigned u = __float_as_uint(f);
    unsigned r = (u + 0x7FFFu + ((u >> 16) & 1u)) >> 16;
    return (unsigned short)r;
}
static __device__ __forceinline__ float bflo(unsigned u) {
    return __uint_as_float(u << 16);
}
static __device__ __forceinline__ float bfhi(unsigned u) {
    return __uint_as_float(u & 0xFFFF0000u);
}

// ---------------- CSR build ----------------

__global__ __launch_bounds__(256) void count_kernel(const int* __restrict__ ei,
                                                    int* __restrict__ cnt, int E) {
    int e = blockIdx.x * 256 + threadIdx.x;
    if (e < E) atomicAdd(&cnt[ei[E + e]], 1);
}

__global__ __launch_bounds__(ST) void scan_part(const int* __restrict__ cnt,
                                                int* __restrict__ bsum, int n) {
    int chunk = (n + SB - 1) / SB;
    int start = blockIdx.x * chunk;
    int end = min(start + chunk, n);
    int s = 0;
    for (int i = start + (int)threadIdx.x; i < end; i += ST) s += cnt[i];
#pragma unroll
    for (int off = 32; off > 0; off >>= 1) s += __shfl_down(s, off, 64);
    __shared__ int wsum[ST / 64];
    if ((threadIdx.x & 63) == 0) wsum[threadIdx.x >> 6] = s;
    __syncthreads();
    if (threadIdx.x == 0) {
        int t = 0;
#pragma unroll
        for (int w = 0; w < ST / 64; ++w) t += wsum[w];
        bsum[blockIdx.x] = t;
    }
}

__global__ __launch_bounds__(ST) void scan_write(const int* __restrict__ cnt,
                                                 const int* __restrict__ bsum,
                                                 int* __restrict__ rowstart, int n) {
    int b = blockIdx.x;
    int t = threadIdx.x;
    int v = (t < b) ? bsum[t] : 0;
#pragma unroll
    for (int off = 32; off > 0; off >>= 1) v += __shfl_down(v, off, 64);
    __shared__ int wsum[ST / 64];
    __shared__ int blockoff;
    if ((t & 63) == 0) wsum[t >> 6] = v;
    __syncthreads();
    if (t == 0) {
        int s = 0;
#pragma unroll
        for (int w = 0; w < ST / 64; ++w) s += wsum[w];
        blockoff = s;
    }
    int chunk = (n + SB - 1) / SB;
    int start = b * chunk;
    int end = min(start + chunk, n);
    int pt = (chunk + ST - 1) / ST;
    int ts = start + t * pt;
    int te = min(ts + pt, end);
    int ls = 0;
    for (int i = ts; i < te; ++i) ls += cnt[i];
    __shared__ int ss[ST];
    ss[t] = ls;
    __syncthreads();
    for (int off = 1; off < ST; off <<= 1) {
        int vv = (t >= off) ? ss[t - off] : 0;
        __syncthreads();
        ss[t] += vv;
        __syncthreads();
    }
    int run = blockoff + (t == 0 ? 0 : ss[t - 1]);
    for (int i = ts; i < te; ++i) { rowstart[i] = run; run += cnt[i]; }
    if (b == SB - 1 && t == ST - 1) rowstart[n] = blockoff + ss[ST - 1];
}

__global__ __launch_bounds__(256) void fill_kernel(const int* __restrict__ ei,
                                                   const int* __restrict__ rowstart,
                                                   int* __restrict__ cursor,
                                                   int* __restrict__ csr, int E) {
    int e = blockIdx.x * 256 + threadIdx.x;
    if (e < E) {
        int d = ei[E + e];
        int pos = atomicAdd(&cursor[d], 1);
        csr[rowstart[d] + pos] = ei[e];
    }
}

__global__ __launch_bounds__(256) void dinv_kernel(const int* __restrict__ cnt,
                                                   float* __restrict__ dinv, int n) {
    int v = blockIdx.x * 256 + threadIdx.x;
    if (v < n) dinv[v] = rsqrtf((float)(cnt[v] + 1));  // +1 self loop
}

// ---------------- weight prep: Wt[n][k] = bf16(W[k][n]) ----------------

__global__ __launch_bounds__(256) void w_prep(const float* __restrict__ W1,
                                              const float* __restrict__ W2,
                                              const float* __restrict__ W3,
                                              unsigned short* __restrict__ Wt1,
                                              unsigned short* __restrict__ Wt2,
                                              unsigned short* __restrict__ Wt3) {
    const float* W = blockIdx.y == 0 ? W1 : (blockIdx.y == 1 ? W2 : W3);
    unsigned short* Wt = blockIdx.y == 0 ? Wt1 : (blockIdx.y == 1 ? Wt2 : Wt3);
    int idx = blockIdx.x * 256 + threadIdx.x;   // 16384 elems
    int k = idx >> 7, nn = idx & 127;
    Wt[nn * 128 + k] = f2bf(W[idx]);
}

// ---------------- fused LeakyReLU + GEMM via MFMA (bf16 in, f32 acc) -------
// Hb[row][c] = bf16( dinv[row] * sum_k lrelu-act(row,k) * W[k][c] )
// INF32: X is f32 raw activations (apply lrelu here). else: X is bf16,
// lrelu already applied by the producing agg.
// Block: 128 rows x 128 cols, 4 waves; wave = 32 rows x 4 col-tiles.
// LDS in 16B chunks, XOR-swizzled: (row, slot) -> row*16 + (slot ^ (row&15)).

template <bool INF32>
__global__ __launch_bounds__(256) void gemm_mfma(const void* __restrict__ Xv,
                                                 const unsigned short* __restrict__ Wt,
                                                 const float* __restrict__ dinv,
                                                 unsigned short* __restrict__ Hb, int n) {
    __shared__ short8v XsC[128 * 16];   // 32 KB
    __shared__ short8v WsC[128 * 16];   // 32 KB

    int tid = threadIdx.x;
    int rowbase = blockIdx.x * 128;

    if (INF32) {
        const float4* X4 = (const float4*)Xv;
#pragma unroll
        for (int i = 0; i < 8; ++i) {
            int idx = i * 256 + tid;              // 2048 chunks
            int r = idx >> 4, s = idx & 15;
            int rowg = min(rowbase + r, n - 1);
            float4 g0 = X4[(size_t)rowg * 32 + s * 2];
            float4 g1 = X4[(size_t)rowg * 32 + s * 2 + 1];
            short8v v;
            v[0] = f2bf(lrelu(g0.x)); v[1] = f2bf(lrelu(g0.y));
            v[2] = f2bf(lrelu(g0.z)); v[3] = f2bf(lrelu(g0.w));
            v[4] = f2bf(lrelu(g1.x)); v[5] = f2bf(lrelu(g1.y));
            v[6] = f2bf(lrelu(g1.z)); v[7] = f2bf(lrelu(g1.w));
            XsC[r * 16 + (s ^ (r & 15))] = v;
        }
    } else {
        const short8v* X8 = (const short8v*)Xv;
#pragma unroll
        for (int i = 0; i < 8; ++i) {
            int idx = i * 256 + tid;
            int r = idx >> 4, s = idx & 15;
            int rowg = min(rowbase + r, n - 1);
            XsC[r * 16 + (s ^ (r & 15))] = X8[(size_t)rowg * 16 + s];
        }
    }
    const short8v* Wt8 = (const short8v*)Wt;
#pragma unroll
    for (int i = 0; i < 8; ++i) {
        int idx = i * 256 + tid;
        int r = idx >> 4, s = idx & 15;
        WsC[r * 16 + (s ^ (r & 15))] = Wt8[idx];
    }
    __syncthreads();

    int w = tid >> 6;
    int l = tid & 63;
    int ln = l & 31;
    int half = l >> 5;
    int arow = 32 * w + ln;
    int rsw = ln & 15;

    f32x16 acc[4];
#pragma unroll
    for (int c = 0; c < 4; ++c)
#pragma unroll
        for (int r = 0; r < 16; ++r) acc[c][r] = 0.f;

#pragma unroll
    for (int ks = 0; ks < 8; ++ks) {
        int sw = (ks * 2 + half) ^ rsw;
        short8v a = XsC[arow * 16 + sw];
        short8v b0 = WsC[(0 * 32 + ln) * 16 + sw];
        short8v b1 = WsC[(1 * 32 + ln) * 16 + sw];
        short8v b2 = WsC[(2 * 32 + ln) * 16 + sw];
        short8v b3 = WsC[(3 * 32 + ln) * 16 + sw];
        acc[0] = __builtin_amdgcn_mfma_f32_32x32x16_bf16(a, b0, acc[0], 0, 0, 0);
        acc[1] = __builtin_amdgcn_mfma_f32_32x32x16_bf16(a, b1, acc[1], 0, 0, 0);
        acc[2] = __builtin_amdgcn_mfma_f32_32x32x16_bf16(a, b2, acc[2], 0, 0, 0);
        acc[3] = __builtin_amdgcn_mfma_f32_32x32x16_bf16(a, b3, acc[3], 0, 0, 0);
    }

    // C/D layout: col = lane&31, row = (r&3)+8*(r>>2)+4*half
    float dsc[16];
#pragma unroll
    for (int r = 0; r < 16; ++r) {
        int rowt = (r & 3) + 8 * (r >> 2) + 4 * half;
        int grow = rowbase + 32 * w + rowt;
        dsc[r] = (grow < n) ? dinv[grow] : 0.f;
    }
#pragma unroll
    for (int c = 0; c < 4; ++c) {
#pragma unroll
        for (int r = 0; r < 16; ++r) {
            int rowt = (r & 3) + 8 * (r >> 2) + 4 * half;
            int grow = rowbase + 32 * w + rowt;
            if (grow < n)
                Hb[(size_t)grow * DF + c * 32 + ln] = f2bf(acc[c][r] * dsc[r]);
        }
    }
}

// ---------------- aggregation: 1 node per wave, lane = bf16x2 cols ----------
// out[v] = b + dinv[v] * (g[v] + sum_{e: dst=v} g[src]),  g = dinv.*H rows
// MODE 0: write bf16 lrelu(out) (feeds next gemm). MODE 1: write f32 out.

template <int MODE>
__global__ __launch_bounds__(256) void agg_kernel(const unsigned short* __restrict__ H,
                                                  const float* __restrict__ dinv,
                                                  const int* __restrict__ rowstart,
                                                  const int* __restrict__ csr,
                                                  const float* __restrict__ b,
                                                  void* __restrict__ outp, int n) {
    int g = blockIdx.x * 256 + threadIdx.x;
    int v = g >> 6;
    int l = g & 63;
    if (v >= n) return;
    const unsigned* H32 = (const unsigned*)H;   // 64 u32 per row
    float dv = dinv[v];
    unsigned su = H32[(size_t)v * 64 + l];
    float2 a0, a1, a2, a3;
    a0.x = bflo(su); a0.y = bfhi(su);
    a1 = make_float2(0.f, 0.f);
    a2 = make_float2(0.f, 0.f);
    a3 = make_float2(0.f, 0.f);
    int j0 = rowstart[v], j1 = rowstart[v + 1];
    int j = j0;
    for (; j + 3 < j1; j += 4) {
        int s0 = csr[j + 0];
        int s1 = csr[j + 1];
        int s2 = csr[j + 2];
        int s3 = csr[j + 3];
        unsigned u0 = H32[(size_t)s0 * 64 + l];
        unsigned u1 = H32[(size_t)s1 * 64 + l];
        unsigned u2 = H32[(size_t)s2 * 64 + l];
        unsigned u3 = H32[(size_t)s3 * 64 + l];
        a0.x += bflo(u0); a0.y += bfhi(u0);
        a1.x += bflo(u1); a1.y += bfhi(u1);
        a2.x += bflo(u2); a2.y += bfhi(u2);
        a3.x += bflo(u3); a3.y += bfhi(u3);
    }
    for (; j < j1; ++j) {
        int s = csr[j];
        unsigned u = H32[(size_t)s * 64 + l];
        a0.x += bflo(u); a0.y += bfhi(u);
    }
    float2 bb = ((const float2*)b)[l];
    float rx = bb.x + dv * ((a0.x + a1.x) + (a2.x + a3.x));
    float ry = bb.y + dv * ((a0.y + a1.y) + (a2.y + a3.y));
    if (MODE == 0) {
        rx = lrelu(rx);
        ry = lrelu(ry);
        unsigned pu = ((unsigned)f2bf(ry) << 16) | (unsigned)f2bf(rx);
        ((unsigned*)outp)[(size_t)v * 64 + l] = pu;
    } else {
        ((float2*)outp)[(size_t)v * 64 + l] = make_float2(rx, ry);
    }
}

extern "C" void kernel_launch(void* const* d_in, const int* in_sizes, int n_in,
                              void* d_out, int out_size, void* d_ws, size_t ws_size,
                              hipStream_t stream) {
    const float* x = (const float*)d_in[0];
    const int* ei = (const int*)d_in[1];
    const float* W1 = (const float*)d_in[2];
    const float* b1 = (const float*)d_in[3];
    const float* W2 = (const float*)d_in[4];
    const float* b2 = (const float*)d_in[5];
    const float* W3 = (const float*)d_in[6];
    const float* b3 = (const float*)d_in[7];
    float* out = (float*)d_out;

    const int N = in_sizes[0] / DF;
    const int E = in_sizes[1] / 2;

    char* ws = (char*)d_ws;
    size_t off = 0;
    auto alloc = [&](size_t bytes) {
        size_t o = off;
        off = (off + bytes + 15) & ~(size_t)15;
        return o;
    };
    int* cnt              = (int*)(ws + alloc((size_t)N * 4));
    int* cursor           = (int*)(ws + alloc((size_t)N * 4));
    float* dinv           = (float*)(ws + alloc((size_t)N * 4));
    int* rowstart         = (int*)(ws + alloc((size_t)(N + 1) * 4));
    int* bsum             = (int*)(ws + alloc((size_t)SB * 4));
    int* csr              = (int*)(ws + alloc((size_t)E * 4));
    unsigned short* Hb    = (unsigned short*)(ws + alloc((size_t)N * DF * 2));
    unsigned short* A     = (unsigned short*)(ws + alloc((size_t)N * DF * 2));
    unsigned short* Wt1   = (unsigned short*)(ws + alloc((size_t)DF * DF * 2));
    unsigned short* Wt2   = (unsigned short*)(ws + alloc((size_t)DF * DF * 2));
    unsigned short* Wt3   = (unsigned short*)(ws + alloc((size_t)DF * DF * 2));

    // zero cnt + cursor (adjacent at the front of ws)
    hipMemsetAsync(ws, 0, (size_t)N * 8, stream);

    w_prep<<<dim3(DF * DF / 256, 3), 256, 0, stream>>>(W1, W2, W3, Wt1, Wt2, Wt3);

    int eb = (E + 255) / 256;
    count_kernel<<<eb, 256, 0, stream>>>(ei, cnt, E);
    scan_part<<<SB, ST, 0, stream>>>(cnt, bsum, N);
    scan_write<<<SB, ST, 0, stream>>>(cnt, bsum, rowstart, N);
    fill_kernel<<<eb, 256, 0, stream>>>(ei, rowstart, cursor, csr, E);
    dinv_kernel<<<(N + 255) / 256, 256, 0, stream>>>(cnt, dinv, N);

    int gemm_blocks = (N + 127) / 128;
    int agg_blocks = (N * 64 + 255) / 256;

    // layer 1
    gemm_mfma<true><<<gemm_blocks, 256, 0, stream>>>(x, Wt1, dinv, Hb, N);
    agg_kernel<0><<<agg_blocks, 256, 0, stream>>>(Hb, dinv, rowstart, csr, b1, A, N);
    // layer 2
    gemm_mfma<false><<<gemm_blocks, 256, 0, stream>>>(A, Wt2, dinv, Hb, N);
    agg_kernel<0><<<agg_blocks, 256, 0, stream>>>(Hb, dinv, rowstart, csr, b2, A, N);
    // layer 3
    gemm_mfma<false><<<gemm_blocks, 256, 0, stream>>>(A, Wt3, dinv, Hb, N);
    agg_kernel<1><<<agg_blocks, 256, 0, stream>>>(Hb, dinv, rowstart, csr, b3, out, N);
}